// Round 10
// baseline (191.910 us; speedup 1.0000x reference)
//
#include <hip/hip_runtime.h>
#include <hip/hip_bf16.h>
#include <math.h>

#define T_TOK 2048
#define H_DIM 2048
#define E_EXP 16
#define I_DIM 512
#define TWO_I 1024
#define ROUTED_SCALE 1.5f
#define SWIGLU_LIMIT 7.0f

#define BM 64
#define KC 64
#define MAX_TILES 80

typedef __attribute__((ext_vector_type(8))) short bf16x8;
typedef __attribute__((ext_vector_type(4))) float f32x4;
typedef unsigned short u16;

__device__ inline u16 f2bf(float f) {
    return __builtin_bit_cast(u16, __float2bfloat16(f));
}
__device__ inline ushort4 pack4(float4 a) {
    ushort4 v;
    v.x = f2bf(a.x); v.y = f2bf(a.y); v.z = f2bf(a.z); v.w = f2bf(a.w);
    return v;
}

// async 16B/lane global->LDS DMA
__device__ inline void gload16(const u16* g, u16* l) {
    __builtin_amdgcn_global_load_lds(
        (const __attribute__((address_space(1))) void*)(g),
        (__attribute__((address_space(3))) void*)(l), 16, 0, 0);
}
#define SCHED0() __builtin_amdgcn_sched_barrier(0)

// swizzled ushort index for 64-elem bf16 rows: logical (row,k) -> row*64 + (k ^ ((row&7)<<3))
#define SWZ(row, k) ((row) * 64 + ((k) ^ (((row) & 7) << 3)))

// ---------------- router: one wave per token; also emits hs in bf16 ----------------
__global__ __launch_bounds__(256) void router_kernel(
    const float* __restrict__ hs, const float* __restrict__ gw,
    const float* __restrict__ bias, int* cnt, int* tok_list, float* w_list,
    u16* __restrict__ hs_bf)
{
    int wave = threadIdx.x >> 6;
    int lane = threadIdx.x & 63;
    int t = blockIdx.x * 4 + wave;
    if (t >= T_TOK) return;
    const float* x = hs + (size_t)t * H_DIM;

    float acc[E_EXP];
#pragma unroll
    for (int e = 0; e < E_EXP; ++e) acc[e] = 0.f;

#pragma unroll 2
    for (int c = 0; c < 8; ++c) {
        int col = c * 256 + lane * 4;
        float4 xv = *(const float4*)(x + col);
        *(ushort4*)(hs_bf + (size_t)t * H_DIM + col) = pack4(xv);
#pragma unroll
        for (int e = 0; e < E_EXP; ++e) {
            float4 gv = *(const float4*)(gw + (size_t)e * H_DIM + col);
            acc[e] = fmaf(xv.x, gv.x, acc[e]);
            acc[e] = fmaf(xv.y, gv.y, acc[e]);
            acc[e] = fmaf(xv.z, gv.z, acc[e]);
            acc[e] = fmaf(xv.w, gv.w, acc[e]);
        }
    }
#pragma unroll
    for (int e = 0; e < E_EXP; ++e) {
        for (int m = 32; m >= 1; m >>= 1)
            acc[e] += __shfl_xor(acc[e], m, 64);
    }
    if (lane == 0) {
        float sc[E_EXP], bsc[E_EXP];
#pragma unroll
        for (int e = 0; e < E_EXP; ++e) {
            sc[e] = 1.f / (1.f + expf(-acc[e]));
            bsc[e] = sc[e] + bias[e];
        }
        int e0 = 0; float b0 = bsc[0];
#pragma unroll
        for (int e = 1; e < E_EXP; ++e) if (bsc[e] > b0) { b0 = bsc[e]; e0 = e; }
        int e1 = -1; float b1 = -1e30f;
#pragma unroll
        for (int e = 0; e < E_EXP; ++e) {
            if (e == e0) continue;
            if (bsc[e] > b1) { b1 = bsc[e]; e1 = e; }
        }
        float s0 = sc[e0], s1 = sc[e1];
        float inv = ROUTED_SCALE / (s0 + s1);
        int p0 = atomicAdd(&cnt[e0], 1);
        tok_list[e0 * T_TOK + p0] = t;
        w_list[e0 * T_TOK + p0] = s0 * inv;
        int p1 = atomicAdd(&cnt[e1], 1);
        tok_list[e1 * T_TOK + p1] = t;
        w_list[e1 * T_TOK + p1] = s1 * inv;
    }
}

// ---------------- fused: compact assignments + tile descriptors ----------------
__global__ void scatter_build(const int* __restrict__ cnt,
    const int* __restrict__ tok_list, const float* __restrict__ w_list,
    int* A_tok, float* A_w, int* tile_e, int* tile_r0)
{
    int c[E_EXP], offs[E_EXP + 1];
    offs[0] = 0;
#pragma unroll
    for (int e = 0; e < E_EXP; ++e) {
        c[e] = cnt[e];
        offs[e + 1] = offs[e] + ((c[e] + BM - 1) & ~(BM - 1));
    }
    int idx = blockIdx.x * 256 + threadIdx.x;
    int e = idx >> 11;
    int pos = idx & (T_TOK - 1);
    int ce = c[e];
    int pe = (ce + BM - 1) & ~(BM - 1);
    if (pos < ce) {
        A_tok[offs[e] + pos] = tok_list[idx];
        A_w[offs[e] + pos] = w_list[idx];
    } else if (pos < pe) {
        A_tok[offs[e] + pos] = -1;
        A_w[offs[e] + pos] = 0.f;
    }
    if (idx == 0) {
        int nt = 0;
        for (int ee = 0; ee < E_EXP; ++ee) {
            int ntile = (c[ee] + BM - 1) >> 6;
            for (int j = 0; j < ntile; ++j) {
                tile_e[nt] = ee;
                tile_r0[nt] = offs[ee] + j * BM;
                ++nt;
            }
        }
        for (; nt < MAX_TILES; ++nt) tile_e[nt] = -1;
    }
}

// ---------------- GEMM1: r5 structure + depth-2 W prefetch + counted vmcnt ----------------
__global__ __launch_bounds__(256, 3) void gemm1_act(
    const u16* __restrict__ hs_bf, const float* __restrict__ w13,
    const int* __restrict__ A_tok, const int* __restrict__ tile_e,
    const int* __restrict__ tile_r0, u16* __restrict__ act)
{
    int b = blockIdx.x;
    int id = (b & 7) * 80 + (b >> 3);      // XCD-chunked bijective swizzle (640 = 8*80)
    int tile = id % MAX_TILES;
    int y = id / MAX_TILES;                // 0..7
    int e = tile_e[tile];
    if (e < 0) return;
    int row0 = tile_r0[tile];
    int i0 = y * 64;
    int tid = threadIdx.x;

    __shared__ u16 Xs[2][4096];
    __shared__ u16 Gs[2][4096];
    __shared__ u16 Us[2][4096];

    const int l = tid & 63, w = tid >> 6;

    // ---- X staging via global_load_lds (pre-swizzled source, linear dest) ----
    const int rlo = l >> 3;
    const int c8 = (l & 7) << 3;
    const int ksrc = c8 ^ (rlo << 3);
    const int rowA = w * 16 + rlo;
    const int rowB = rowA + 8;
    int tokA = A_tok[row0 + rowA]; if (tokA < 0) tokA = 0;
    int tokB = A_tok[row0 + rowB]; if (tokB < 0) tokB = 0;
    const u16* sXA = hs_bf + (size_t)tokA * H_DIM + ksrc;
    const u16* sXB = hs_bf + (size_t)tokB * H_DIM + ksrc;
    const int dA = w * 1024;

#define X_STAGE(bb, t) do { int ko = (t) * KC; \
    gload16(sXA + ko, &Xs[bb][dA]);  gload16(sXB + ko, &Xs[bb][dA + 512]); } while (0)

    // ---- weight staging: fp32 loads -> two reg sets -> bf16 -> swizzled ds_write ----
    const int srow = tid >> 4;             // 0..15
    const int sc4  = tid & 15;
    const int kphys = (sc4 * 4) ^ ((srow & 7) << 3);
    const int sbase = srow * 64 + kphys;
    const float* gsrc = w13 + ((size_t)e * TWO_I + i0 + srow) * H_DIM + sc4 * 4;
    const float* usrc = gsrc + (size_t)I_DIM * H_DIM;

    float4 gA[4], uA[4], gB[4], uB[4];
#define W_LOAD(S, t) do { int k0 = (t) * KC; \
    g##S[0] = *(const float4*)(gsrc + k0); \
    g##S[1] = *(const float4*)(gsrc + k0 + 16 * H_DIM); \
    g##S[2] = *(const float4*)(gsrc + k0 + 32 * H_DIM); \
    g##S[3] = *(const float4*)(gsrc + k0 + 48 * H_DIM); \
    u##S[0] = *(const float4*)(usrc + k0); \
    u##S[1] = *(const float4*)(usrc + k0 + 16 * H_DIM); \
    u##S[2] = *(const float4*)(usrc + k0 + 32 * H_DIM); \
    u##S[3] = *(const float4*)(usrc + k0 + 48 * H_DIM); } while (0)

#define W_WRITE(S, bb) do { \
    *(ushort4*)&Gs[bb][sbase]        = pack4(g##S[0]); \
    *(ushort4*)&Gs[bb][sbase + 1024] = pack4(g##S[1]); \
    *(ushort4*)&Gs[bb][sbase + 2048] = pack4(g##S[2]); \
    *(ushort4*)&Gs[bb][sbase + 3072] = pack4(g##S[3]); \
    *(ushort4*)&Us[bb][sbase]        = pack4(u##S[0]); \
    *(ushort4*)&Us[bb][sbase + 1024] = pack4(u##S[1]); \
    *(ushort4*)&Us[bb][sbase + 2048] = pack4(u##S[2]); \
    *(ushort4*)&Us[bb][sbase + 3072] = pack4(u##S[3]); } while (0)

    // ---- MFMA roles: 4 waves as 2x2 over (token32, i32) ----
    const int wm = w >> 1, wn = w & 1;
    const int lr = l & 15;
    const int lg = l >> 4;
    const int ra0 = wm * 32 + lr, ra1 = ra0 + 16;
    const int rb0 = wn * 32 + lr, rb1 = rb0 + 16;
    int ia0[2], ia1[2], ib0[2], ib1[2];
#pragma unroll
    for (int kh = 0; kh < 2; ++kh) {
        int e2 = kh * 32 + lg * 8;
        ia0[kh] = SWZ(ra0, e2); ia1[kh] = SWZ(ra1, e2);
        ib0[kh] = SWZ(rb0, e2); ib1[kh] = SWZ(rb1, e2);
    }

    const f32x4 Z4 = {0.f, 0.f, 0.f, 0.f};
    f32x4 aG[2][2], aU[2][2];
#pragma unroll
    for (int m = 0; m < 2; ++m)
#pragma unroll
        for (int n = 0; n < 2; ++n) { aG[m][n] = Z4; aU[m][n] = Z4; }

#define MFMA_STEP(c) do { \
    _Pragma("unroll") for (int kh = 0; kh < 2; ++kh) { \
        bf16x8 a0 = *(const bf16x8*)&Xs[c][ia0[kh]]; \
        bf16x8 a1 = *(const bf16x8*)&Xs[c][ia1[kh]]; \
        bf16x8 g0 = *(const bf16x8*)&Gs[c][ib0[kh]]; \
        bf16x8 g1 = *(const bf16x8*)&Gs[c][ib1[kh]]; \
        bf16x8 u0 = *(const bf16x8*)&Us[c][ib0[kh]]; \
        bf16x8 u1 = *(const bf16x8*)&Us[c][ib1[kh]]; \
        aG[0][0] = __builtin_amdgcn_mfma_f32_16x16x32_bf16(a0, g0, aG[0][0], 0, 0, 0); \
        aG[0][1] = __builtin_amdgcn_mfma_f32_16x16x32_bf16(a0, g1, aG[0][1], 0, 0, 0); \
        aG[1][0] = __builtin_amdgcn_mfma_f32_16x16x32_bf16(a1, g0, aG[1][0], 0, 0, 0); \
        aG[1][1] = __builtin_amdgcn_mfma_f32_16x16x32_bf16(a1, g1, aG[1][1], 0, 0, 0); \
        aU[0][0] = __builtin_amdgcn_mfma_f32_16x16x32_bf16(a0, u0, aU[0][0], 0, 0, 0); \
        aU[0][1] = __builtin_amdgcn_mfma_f32_16x16x32_bf16(a0, u1, aU[0][1], 0, 0, 0); \
        aU[1][0] = __builtin_amdgcn_mfma_f32_16x16x32_bf16(a1, u0, aU[1][0], 0, 0, 0); \
        aU[1][1] = __builtin_amdgcn_mfma_f32_16x16x32_bf16(a1, u1, aU[1][1], 0, 0, 0); \
    } } while (0)

    const int NT = H_DIM / KC;             // 32 (even)
    // prologue: queue = [X0:2, WA(0):8, X1:2, WB(1):8]
    X_STAGE(0, 0);
    W_LOAD(A, 0);
    X_STAGE(1, 1);
    W_LOAD(B, 1);
    W_WRITE(A, 0);                          // compiler waits vmcnt(10): X0+WA drained
    asm volatile("s_waitcnt lgkmcnt(0)" ::: "memory");
    SCHED0();
    __builtin_amdgcn_s_barrier();

    for (int t = 0; t < NT; t += 2) {
        {   // iter t (even): mfma buf0; stage X(t+1)->buf1; load W(t+2)->A; write W(t+1) from B
            int ts = (t + 1 < NT) ? t + 1 : NT - 1;
            int tx = (t + 2 < NT) ? t + 2 : NT - 1;
            X_STAGE(1, ts);
            W_LOAD(A, tx);
            SCHED0();
            MFMA_STEP(0);
            W_WRITE(B, 1);                  // compiler: counted vmcnt for B regs
            asm volatile("s_waitcnt vmcnt(8) lgkmcnt(0)" ::: "memory");  // X landed; W(t+2) stays in flight
            SCHED0();
            __builtin_amdgcn_s_barrier();
        }
        {   // iter t+1 (odd): mfma buf1; stage X(t+2)->buf0; load W(t+3)->B; write W(t+2) from A
            int ts = (t + 2 < NT) ? t + 2 : NT - 1;
            int tx = (t + 3 < NT) ? t + 3 : NT - 1;
            X_STAGE(0, ts);
            W_LOAD(B, tx);
            SCHED0();
            MFMA_STEP(1);
            W_WRITE(A, 0);
            asm volatile("s_waitcnt vmcnt(8) lgkmcnt(0)" ::: "memory");
            SCHED0();
            __builtin_amdgcn_s_barrier();
        }
    }
#undef X_STAGE
#undef W_LOAD
#undef W_WRITE
#undef MFMA_STEP

#pragma unroll
    for (int m = 0; m < 2; ++m)
#pragma unroll
        for (int n = 0; n < 2; ++n) {
            int col = i0 + wn * 32 + n * 16 + lr;
            int rbase = row0 + wm * 32 + m * 16 + lg * 4;
#pragma unroll
            for (int q = 0; q < 4; ++q) {
                float g = fminf(aG[m][n][q], SWIGLU_LIMIT);
                float u = fminf(fmaxf(aU[m][n][q], -SWIGLU_LIMIT), SWIGLU_LIMIT);
                float s = 1.f / (1.f + __expf(-g));
                act[(size_t)(rbase + q) * I_DIM + col] = f2bf(g * s * u);
            }
        }
}

// ---------------- GEMM2: r5 structure + depth-2 B prefetch + counted vmcnt ----------------
__global__ __launch_bounds__(256, 4) void gemm2_scatter(
    const u16* __restrict__ act, const float* __restrict__ w2,
    const int* __restrict__ A_tok, const float* __restrict__ A_w,
    const int* __restrict__ tile_e, const int* __restrict__ tile_r0,
    float* __restrict__ out)
{
    int b = blockIdx.x;
    int id = (b & 7) * 320 + (b >> 3);     // 2560 = 8*320
    int tile = id % MAX_TILES;
    int y = id / MAX_TILES;                // 0..31
    int e = tile_e[tile];
    if (e < 0) return;
    int row0 = tile_r0[tile];
    int h0 = y * 64;
    int tid = threadIdx.x;

    __shared__ u16 As[2][4096];
    __shared__ u16 Bs[2][4096];

    const int l = tid & 63, w = tid >> 6;

    const int rlo = l >> 3;
    const int c8 = (l & 7) << 3;
    const int ksrc = c8 ^ (rlo << 3);
    const int rowA = w * 16 + rlo;
    const int rowB = rowA + 8;
    const u16* sAA = act + (size_t)(row0 + rowA) * I_DIM + ksrc;
    const u16* sAB = act + (size_t)(row0 + rowB) * I_DIM + ksrc;
    const int dA = w * 1024;

#define A_STAGE(bb, t) do { int ko = (t) * KC; \
    gload16(sAA + ko, &As[bb][dA]);  gload16(sAB + ko, &As[bb][dA + 512]); } while (0)

    const int srow = tid >> 4;
    const int sc4  = tid & 15;
    const int kphys = (sc4 * 4) ^ ((srow & 7) << 3);
    const int sbase = srow * 64 + kphys;
    const float* bsrc = w2 + ((size_t)e * H_DIM + h0 + srow) * I_DIM + sc4 * 4;

    float4 bA[4], bB[4];
#define B_LOAD(S, t) do { int k0 = (t) * KC; \
    b##S[0] = *(const float4*)(bsrc + k0); \
    b##S[1] = *(const float4*)(bsrc + k0 + 16 * I_DIM); \
    b##S[2] = *(const float4*)(bsrc + k0 + 32 * I_DIM); \
    b##S[3] = *(const float4*)(bsrc + k0 + 48 * I_DIM); } while (0)

#define B_WRITE(S, bb) do { \
    *(ushort4*)&Bs[bb][sbase]        = pack4(b##S[0]); \
    *(ushort4*)&Bs[bb][sbase + 1024] = pack4(b##S[1]); \
    *(ushort4*)&Bs[bb][sbase + 2048] = pack4(b##S[2]); \
    *(ushort4*)&Bs[bb][sbase + 3072] = pack4(b##S[3]); } while (0)

    const int wm = w >> 1, wn = w & 1;
    const int lr = l & 15;
    const int lg = l >> 4;
    const int ra0 = wm * 32 + lr, ra1 = ra0 + 16;
    const int rb0 = wn * 32 + lr, rb1 = rb0 + 16;
    int ia0[2], ia1[2], ib0[2], ib1[2];
#pragma unroll
    for (int kh = 0; kh < 2; ++kh) {
        int e2 = kh * 32 + lg * 8;
        ia0[kh] = SWZ(ra0, e2); ia1[kh] = SWZ(ra1, e2);
        ib0[kh] = SWZ(rb0, e2); ib1[kh] = SWZ(rb1, e2);
    }

    const f32x4 Z4 = {0.f, 0.f, 0.f, 0.f};
    f32x4 acc[2][2];
#pragma unroll
    for (int m = 0; m < 2; ++m)
#pragma unroll
        for (int n = 0; n < 2; ++n) acc[m][n] = Z4;

#define MFMA_STEP(c) do { \
    _Pragma("unroll") for (int kh = 0; kh < 2; ++kh) { \
        bf16x8 a0 = *(const bf16x8*)&As[c][ia0[kh]]; \
        bf16x8 a1 = *(const bf16x8*)&As[c][ia1[kh]]; \
        bf16x8 b0 = *(const bf16x8*)&Bs[c][ib0[kh]]; \
        bf16x8 b1 = *(const bf16x8*)&Bs[c][ib1[kh]]; \
        acc[0][0] = __builtin_amdgcn_mfma_f32_16x16x32_bf16(a0, b0, acc[0][0], 0, 0, 0); \
        acc[0][1] = __builtin_amdgcn_mfma_f32_16x16x32_bf16(a0, b1, acc[0][1], 0, 0, 0); \
        acc[1][0] = __builtin_amdgcn_mfma_f32_16x16x32_bf16(a1, b0, acc[1][0], 0, 0, 0); \
        acc[1][1] = __builtin_amdgcn_mfma_f32_16x16x32_bf16(a1, b1, acc[1][1], 0, 0, 0); \
    } } while (0)

    const int NT = I_DIM / KC;             // 8 (even)
    A_STAGE(0, 0);
    B_LOAD(A, 0);
    A_STAGE(1, 1);
    B_LOAD(B, 1);
    B_WRITE(A, 0);                          // compiler waits vmcnt(6)
    asm volatile("s_waitcnt lgkmcnt(0)" ::: "memory");
    SCHED0();
    __builtin_amdgcn_s_barrier();

    for (int t = 0; t < NT; t += 2) {
        {
            int ts = (t + 1 < NT) ? t + 1 : NT - 1;
            int tx = (t + 2 < NT) ? t + 2 : NT - 1;
            A_STAGE(1, ts);
            B_LOAD(A, tx);
            SCHED0();
            MFMA_STEP(0);
            B_WRITE(B, 1);
            asm volatile("s_waitcnt vmcnt(4) lgkmcnt(0)" ::: "memory");
            SCHED0();
            __builtin_amdgcn_s_barrier();
        }
        {
            int ts = (t + 2 < NT) ? t + 2 : NT - 1;
            int tx = (t + 3 < NT) ? t + 3 : NT - 1;
            A_STAGE(0, ts);
            B_LOAD(B, tx);
            SCHED0();
            MFMA_STEP(1);
            B_WRITE(A, 0);
            asm volatile("s_waitcnt vmcnt(4) lgkmcnt(0)" ::: "memory");
            SCHED0();
            __builtin_amdgcn_s_barrier();
        }
    }
#undef A_STAGE
#undef B_LOAD
#undef B_WRITE
#undef MFMA_STEP

    // epilogue: per-slot combine weight from global
#pragma unroll
    for (int m = 0; m < 2; ++m)
#pragma unroll
        for (int n = 0; n < 2; ++n) {
            int col = h0 + wn * 32 + n * 16 + lr;
            int sbase2 = wm * 32 + m * 16 + lg * 4;
#pragma unroll
            for (int q = 0; q < 4; ++q) {
                int slot = row0 + sbase2 + q;
                int tok = A_tok[slot];
                if (tok >= 0)
                    atomicAdd(&out[(size_t)tok * H_DIM + col], acc[m][n][q] * A_w[slot]);
            }
        }
}

extern "C" void kernel_launch(void* const* d_in, const int* in_sizes, int n_in,
                              void* d_out, int out_size, void* d_ws, size_t ws_size,
                              hipStream_t stream) {
    const float* hs   = (const float*)d_in[0];
    const float* gw   = (const float*)d_in[1];
    const float* bias = (const float*)d_in[2];
    const float* w13  = (const float*)d_in[3];
    const float* w2   = (const float*)d_in[4];
    float* out = (float*)d_out;

    char* ws = (char*)d_ws;
    int*   cnt      = (int*)(ws + 0);
    int*   tile_e   = (int*)(ws + 64);
    int*   tile_r0  = (int*)(ws + 384);
    int*   tok_list = (int*)(ws + 1024);
    float* w_list   = (float*)(ws + 132096);
    int*   A_tok    = (int*)(ws + 263168);
    float* A_w      = (float*)(ws + 283648);
    u16*   act      = (u16*)(ws + 304128);       // 5 MB
    u16*   hs_bf    = (u16*)(ws + 5547008);      // 8 MB -> ~13.6 MB total

    hipMemsetAsync(d_out, 0, (size_t)T_TOK * H_DIM * sizeof(float), stream);
    hipMemsetAsync(cnt, 0, 64, stream);

    router_kernel<<<T_TOK / 4, 256, 0, stream>>>(hs, gw, bias, cnt, tok_list, w_list, hs_bf);
    scatter_build<<<(E_EXP * T_TOK) / 256, 256, 0, stream>>>(cnt, tok_list, w_list, A_tok, A_w, tile_e, tile_r0);

    gemm1_act<<<MAX_TILES * 8, 256, 0, stream>>>(hs_bf, w13, A_tok, tile_e, tile_r0, act);
    gemm2_scatter<<<MAX_TILES * 32, 256, 0, stream>>>(act, w2, A_tok, A_w, tile_e, tile_r0, out);
}